// Round 11
// baseline (195.900 us; speedup 1.0000x reference)
//
#include <hip/hip_runtime.h>
#include <hip/hip_bf16.h>

// B=8, N=256, D=128, E=32, H=4, HD=32
// ws layout (float/u32 offsets)
#define OFF_WQT 0          // 16384 transposed wq  [k][d]
#define OFF_WKT 16384
#define OFF_WVT 32768
#define OFF_OWT 49152      // transposed out_w [k][d]
#define OFF_GWT 65536      // transposed gcn_w [k][d]
#define OFF_WKE 81920      // 4096: wk@edge_w, row-major [d][e]
#define OFF_WVET 86016     // 4096: (wv@edge_w)^T, [e][d]
#define OFF_KB  90112      // 128 f32
#define OFF_VB  90240      // 128 f32
#define OFF_SC  90368      // 8192: per-row per-head score const
#define OFF_QSP 98560      // 131072 u32: q/sqrt(HD) packed f16 pairs (64/row)
#define OFF_QEP 229632     // 131072 u32: qe packed f16 pairs
#define OFF_HG  360704     // 262144 f32: gcn branch output (incl gcn_b)
#define OFF_K0P 622848     // 131072 u32: K0 packed f16 (64/row)
#define OFF_V0P 753920     // 131072 u32: V0 packed f16
// total 885 Kf = 3.54 MB

// gfx950 builtins use the __fp16 ext-vector type (NOT _Float16)
using half2_t = __attribute__((ext_vector_type(2))) __fp16;

static __device__ __forceinline__ half2_t u2h(unsigned int u){
  union { unsigned int u; half2_t h; } x; x.u = u; return x.h;
}
static __device__ __forceinline__ unsigned int pkf16(float a, float b){
  union { half2_t h; unsigned int u; } x;
  x.h = __builtin_amdgcn_cvt_pkrtz(a, b);
  return x.u;
}
static __device__ __forceinline__ float fdot2(unsigned int a, unsigned int b, float c){
  return __builtin_amdgcn_fdot2(u2h(a), u2h(b), c, false);
}

// ---------------------------------------------------------------------------
// Kernel A (prep): 5 weight transposes + Wke / WveT + fused biases.
// ---------------------------------------------------------------------------
__global__ __launch_bounds__(256) void prep_kernel(
    const float* __restrict__ wq, const float* __restrict__ wk,
    const float* __restrict__ wv, const float* __restrict__ out_w,
    const float* __restrict__ gcn_w, const float* __restrict__ edge_w,
    const float* __restrict__ edge_b, const float* __restrict__ bk,
    const float* __restrict__ bv, float* __restrict__ ws)
{
  int blk = blockIdx.x, t = threadIdx.x;
  if (blk < 320) {
    int w = blk >> 6;
    int e0 = (blk & 63) * 256 + t;
    const float* src = (w==0) ? wq : (w==1) ? wk : (w==2) ? wv : (w==3) ? out_w : gcn_w;
    float* dst = ws + ((w==0) ? OFF_WQT : (w==1) ? OFF_WKT : (w==2) ? OFF_WVT
                      : (w==3) ? OFF_OWT : OFF_GWT);
    int k = e0 >> 7, d = e0 & 127;
    dst[e0] = src[d*128 + k];
  } else if (blk < 352) {
    int idx = blk - 320;
    int which = idx >> 4;                  // 0: Wke (row-major), 1: WveT (transposed)
    int e0 = (idx & 15) * 256 + t;
    int dd = e0 >> 5, e = e0 & 31;
    const float* W = which ? wv : wk;
    float acc = 0.f;
    #pragma unroll 4
    for (int k2 = 0; k2 < 128; ++k2) acc += W[dd*128+k2] * edge_w[k2*32+e];
    if (which) ws[OFF_WVET + e*128 + dd] = acc;
    else       ws[OFF_WKE + e0] = acc;
  } else {
    int dd = t & 127;
    const float* W  = (t < 128) ? wk : wv;
    const float* bb = (t < 128) ? bk : bv;
    float acc = bb[dd];
    #pragma unroll 4
    for (int k2 = 0; k2 < 128; ++k2) acc += W[dd*128+k2] * edge_b[k2];
    ws[((t < 128) ? OFF_KB : OFF_VB) + dd] = acc;
  }
}

// ---------------------------------------------------------------------------
// Kernel B (proj) = v1 (2 rows/block, grid 1024).
// ---------------------------------------------------------------------------
__global__ __launch_bounds__(256) void proj_kernel(
    const float* __restrict__ h, const float* __restrict__ adj,
    const float* __restrict__ bq, const float* __restrict__ gcn_b,
    float* __restrict__ ws)
{
  __shared__ float h_lds[256];        // 2 x 128
  __shared__ float adj_lds[512];      // 2 x 256
  __shared__ float p1[2][2][128];
  __shared__ float p2[2][2][128];
  __shared__ float p3[2][2][128];
  __shared__ float qrow[2*132];
  __shared__ float qe_l[2*132];
  __shared__ float dpart[2][2];
  __shared__ float ha_lds[2*132];

  int t = threadIdx.x;
  int d = t & 127, kh = t >> 7;
  int r0 = blockIdx.x * 2;
  int b  = r0 >> 8, n0 = r0 & 255;
  unsigned int* wsu = (unsigned int*)ws;

  if (t < 64)  ((float4*)h_lds)[t]   = ((const float4*)(h   + (size_t)r0*128))[t];
  if (t < 128) ((float4*)adj_lds)[t] = ((const float4*)(adj + (size_t)r0*256))[t];
  __syncthreads();

  // --- A: qkv matvecs, transposed weights (lane-d coalesced) ---
  {
    const float* wqT = ws + OFF_WQT;
    const float* wkT = ws + OFF_WKT;
    const float* wvT = ws + OFF_WVT;
    float aq0=0,aq1=0,ak0=0,ak1=0,av0=0,av1=0;
    #pragma unroll 4
    for (int kk = 0; kk < 64; ++kk) {
      int k = kh*64 + kk;
      float qw = wqT[k*128+d], kw = wkT[k*128+d], vw = wvT[k*128+d];
      float h0 = h_lds[k], h1 = h_lds[128+k];
      aq0 += qw*h0; aq1 += qw*h1;
      ak0 += kw*h0; ak1 += kw*h1;
      av0 += vw*h0; av1 += vw*h1;
    }
    p1[kh][0][d]=aq0; p1[kh][1][d]=aq1;
    p2[kh][0][d]=ak0; p2[kh][1][d]=ak1;
    p3[kh][0][d]=av0; p3[kh][1][d]=av1;
  }
  __syncthreads();

  // --- B: qrow (f32 LDS) + K/V pack to global ---
  {
    int i = t >> 7, dd = t & 127;
    const float inv = 0.17677669529663687f;   // 1/sqrt(32)
    qrow[i*132 + dd] = (p1[0][i][dd] + p1[1][i][dd] + bq[dd]) * inv;
  }
  {
    int i = (t >> 6) & 1, pr = t & 63;
    if (t < 128) {
      float k0 = p2[0][i][2*pr] + p2[1][i][2*pr];
      float k1 = p2[0][i][2*pr+1] + p2[1][i][2*pr+1];
      wsu[OFF_K0P + (size_t)(r0+i)*64 + pr] = pkf16(k0, k1);
    } else {
      float v0 = p3[0][i][2*pr] + p3[1][i][2*pr];
      float v1 = p3[0][i][2*pr+1] + p3[1][i][2*pr+1];
      wsu[OFF_V0P + (size_t)(r0+i)*64 + pr] = pkf16(v0, v1);
    }
  }
  __syncthreads();   // qrow ready; p1..p3 free

  // --- C: qs-pack, qe compute, sc, GCN aggregation ---
  if (t < 128) {
    int i = t >> 6, pr = t & 63;
    wsu[OFF_QSP + (size_t)(r0+i)*64 + pr] = pkf16(qrow[i*132 + 2*pr], qrow[i*132 + 2*pr+1]);
  }
  {
    int i = t >> 7, he = t & 127, hh = he >> 5, e = he & 31;
    float acc = 0.f;
    #pragma unroll
    for (int j = 0; j < 32; ++j)
      acc += ws[OFF_WKE + (hh*32 + j)*32 + e] * qrow[i*132 + hh*32 + j];
    qe_l[i*132 + he] = acc;
  }
  if (t < 8) {
    int i = t >> 2, hh = t & 3;
    float acc = 0.f;
    #pragma unroll
    for (int j = 0; j < 32; ++j)
      acc += qrow[i*132 + hh*32 + j] * ws[OFF_KB + hh*32 + j];
    ws[OFF_SC + (size_t)(r0+i)*4 + hh] = acc;
  }
  {
    float ag0=0, ag1=0, dg0=0, dg1=0;
    #pragma unroll 4
    for (int mm = 0; mm < 128; ++mm) {
      int ml = kh*128 + mm;
      float hv = h[((size_t)b*256 + ml)*128 + d];
      float a0 = adj_lds[ml]       + ((ml == n0)     ? 1.0f : 0.0f);
      float a1 = adj_lds[256 + ml] + ((ml == n0 + 1) ? 1.0f : 0.0f);
      ag0 += a0*hv; ag1 += a1*hv; dg0 += a0; dg1 += a1;
    }
    p1[kh][0][d]=ag0; p1[kh][1][d]=ag1;
    if (d == 0) { dpart[kh][0]=dg0; dpart[kh][1]=dg1; }
  }
  __syncthreads();

  // --- D: qe-pack + ha ---
  if (t < 128) {
    int i = t >> 6, pr = t & 63;
    wsu[OFF_QEP + (size_t)(r0+i)*64 + pr] = pkf16(qe_l[i*132 + 2*pr], qe_l[i*132 + 2*pr+1]);
  }
  {
    int i = t >> 7, dd = t & 127;
    ha_lds[i*132 + dd] = (p1[0][i][dd] + p1[1][i][dd]) / (dpart[0][i] + dpart[1][i]);
  }
  __syncthreads();

  // --- E: gcn matvec (transposed, coalesced) ---
  {
    const float* gwT = ws + OFF_GWT;
    float g0=0, g1=0;
    #pragma unroll 4
    for (int kk = 0; kk < 64; ++kk) {
      int k = kh*64 + kk;
      float gw = gwT[k*128+d];
      g0 += gw * ha_lds[k];
      g1 += gw * ha_lds[132 + k];
    }
    p2[kh][0][d]=g0; p2[kh][1][d]=g1;
  }
  __syncthreads();
  {
    int i = t >> 7, dd = t & 127;
    ws[OFF_HG + (size_t)(r0+i)*128 + dd] = p2[0][i][dd] + p2[1][i][dd] + gcn_b[dd];
  }
}

// ---------------------------------------------------------------------------
// Kernel C (attn+epi fused), R11: NO edge LDS staging (Common-mistake #7:
// don't stage what L2-fits). e_buf, pkf16 pack, and prefetch regs all gone.
//  - score: edge row read directly from global as float4 (f32 math, qe
//    unpacked to f32 LDS broadcast); K0 keeps proven packed-f16 fdot2.
//  - p3-ebar: edge column read from global, lanes e=0..31 coalesced per m,
//    L2-hot (score touched the chunk one phase earlier).
//  - s_chunk double-buffered, ONE barrier per chunk (R10 skeleton).
// LDS ~6 KB. Staging write->barrier->read chain eliminated from the
// critical path; score's 8 edge loads are independent and hoistable.
// ---------------------------------------------------------------------------
__global__ __launch_bounds__(256) void attn_kernel(
    const float* __restrict__ edge, const float* __restrict__ adj,
    const float* __restrict__ srcm, const float* __restrict__ h,
    const float* __restrict__ out_b, const float* __restrict__ ln_g,
    const float* __restrict__ ln_b, const float* __restrict__ ws,
    float* __restrict__ out)
{
  __shared__ unsigned int q_lds[64];       // qs packed words
  __shared__ float qe_lds[128];            // qe unpacked f32 [4 heads][32]
  __shared__ float s_chunk[2][4*66];       // unnormalized exp, double-buffered
  __shared__ float wpart[16];
  __shared__ float ovh[128];               // wave-3 ov partials (64 float2)
  __shared__ float eb_l[128];
  __shared__ float ov_l[128];
  __shared__ float o_l[128];
  __shared__ float px[256];
  __shared__ float stat[4];

  const int t  = threadIdx.x;
  const int bn = blockIdx.x;
  const int b  = bn >> 8;
  const int hh = t & 3;
  const int mq = t >> 2;                   // chunk-local row for score phase
  const unsigned int* wsu = (const unsigned int*)ws;

  const float* eg = edge + (size_t)bn*8192;          // f32 edge tile base
  const float4* et = (const float4*)eg;

  // ---- prologue: masks, qs -> LDS, qe unpack -> f32 LDS, tail prefetch ----
  float mp0 = adj[(size_t)bn*256 +       mq] * srcm[(size_t)bn*256 +       mq];
  float mp1 = adj[(size_t)bn*256 +  64 + mq] * srcm[(size_t)bn*256 +  64 + mq];
  float mp2 = adj[(size_t)bn*256 + 128 + mq] * srcm[(size_t)bn*256 + 128 + mq];
  float mp3 = adj[(size_t)bn*256 + 192 + mq] * srcm[(size_t)bn*256 + 192 + mq];

  if (t < 64) {
    q_lds[t] = wsu[OFF_QSP + (size_t)bn*64 + t];
  } else if (t < 128) {
    int idx = t - 64;                      // u32 index: head = idx>>4, j = idx&15
    unsigned int w = wsu[OFF_QEP + (size_t)bn*64 + idx];
    half2_t hv = u2h(w);
    int head = idx >> 4, j = idx & 15;
    qe_lds[head*32 + 2*j]     = (float)hv.x;
    qe_lds[head*32 + 2*j + 1] = (float)hv.y;
  }

  float sconst = ws[OFF_SC + (size_t)bn*4 + hh];
  const unsigned int* K0 = wsu + OFF_K0P + (size_t)b*256*64;

  float h_pre = 0.f, hg_pre = 0.f;
  if (t < 128) {
    h_pre  = h[(size_t)bn*128 + t];
    hg_pre = ws[OFF_HG + (size_t)bn*128 + t];
  }
  __syncthreads();            // q_lds / qe_lds visible

  // persistent accumulators (role-split by wave)
  float exacc = 0.f;
  float acc4 = 0.f;                 // t<128: ebar(ht=t>>5, e=t&31)
  float acc5x = 0.f, acc5y = 0.f;   // t>=128: ov d-pair

  // ---- main loop: 4 chunks, ONE barrier each ----
  #pragma unroll
  for (int c = 0; c < 4; ++c) {
    // score(c): thread (hh, mq) -> ex for chunk row mq
    {
      int gm = c*64 + mq;
      float acc = sconst;
      const uint4* kr4 = (const uint4*)(K0 + (size_t)gm*64 + hh*16);
      const uint4* qs4 = (const uint4*)(q_lds + hh*16);
      #pragma unroll
      for (int j4 = 0; j4 < 4; ++j4) {
        uint4 kw = kr4[j4];
        uint4 qw = qs4[j4];
        acc = fdot2(qw.x, kw.x, acc);
        acc = fdot2(qw.y, kw.y, acc);
        acc = fdot2(qw.z, kw.z, acc);
        acc = fdot2(qw.w, kw.w, acc);
      }
      const float4* erow = et + (size_t)gm*8;        // 32 f32, global (L2/L3)
      const float* qe = qe_lds + hh*32;              // broadcast reads
      #pragma unroll
      for (int j = 0; j < 8; ++j) {
        float4 v = erow[j];
        acc = fmaf(qe[4*j+0], v.x, acc);
        acc = fmaf(qe[4*j+1], v.y, acc);
        acc = fmaf(qe[4*j+2], v.z, acc);
        acc = fmaf(qe[4*j+3], v.w, acc);
      }
      float mp = (c==0) ? mp0 : (c==1) ? mp1 : (c==2) ? mp2 : mp3;
      float ex = (mp == 0.0f) ? 0.0f : __expf(acc);   // no max-sub: |s| << 88
      s_chunk[c & 1][hh*66 + mq] = ex;
      exacc += ex;
    }

    // p3(c-1): register accumulation, wave-split (edge from global, L2-hot)
    if (c > 0) {
      const float* scp = s_chunk[(c-1) & 1];
      if (t < 128) {
        int e = t & 31, ht = t >> 5;
        const float* sc_ = scp + ht*66;
        const float* ecol = eg + ((size_t)(c-1)*64)*32 + e;
        float a0 = 0.f, a1 = 0.f;
        #pragma unroll 8
        for (int m = 0; m < 64; m += 2) {
          a0 = fmaf(sc_[m],   ecol[(size_t)m*32],     a0);
          a1 = fmaf(sc_[m+1], ecol[(size_t)(m+1)*32], a1);
        }
        acc4 += a0 + a1;
      } else {
        int idx = t - 128;
        int j = idx & 63, mh = idx >> 6;
        int head = j >> 4;
        const float* sc_ = scp + head*66 + mh*32;
        const unsigned int* vp = wsu + OFF_V0P + ((size_t)b*256 + (c-1)*64 + mh*32)*64 + j;
        float a0 = 0.f, a1 = 0.f;
        #pragma unroll 8
        for (int m = 0; m < 32; ++m) {
          float s = sc_[m];
          half2_t v = u2h(vp[(size_t)m*64]);
          a0 += s*(float)v.x; a1 += s*(float)v.y;
        }
        acc5x += a0; acc5y += a1;
      }
    }
    __syncthreads();            // one barrier per chunk (s_chunk handoff)
  }

  // ---- exp-sum reduce (same-head lanes within wave) ----
  exacc += __shfl_down(exacc, 4);
  exacc += __shfl_down(exacc, 8);
  exacc += __shfl_down(exacc, 16);
  exacc += __shfl_down(exacc, 32);
  if ((t & 63) < 4) wpart[(t >> 6)*4 + hh] = exacc;

  // ---- p3(3): final chunk accumulation (after loop's last barrier) ----
  {
    const float* scp = s_chunk[1];
    if (t < 128) {
      int e = t & 31, ht = t >> 5;
      const float* sc_ = scp + ht*66;
      const float* ecol = eg + (size_t)192*32 + e;
      float a0 = 0.f, a1 = 0.f;
      #pragma unroll 8
      for (int m = 0; m < 64; m += 2) {
        a0 = fmaf(sc_[m],   ecol[(size_t)m*32],     a0);
        a1 = fmaf(sc_[m+1], ecol[(size_t)(m+1)*32], a1);
      }
      acc4 += a0 + a1;
    } else {
      int idx = t - 128;
      int j = idx & 63, mh = idx >> 6;
      int head = j >> 4;
      const float* sc_ = scp + head*66 + mh*32;
      const unsigned int* vp = wsu + OFF_V0P + ((size_t)b*256 + 192 + mh*32)*64 + j;
      float a0 = 0.f, a1 = 0.f;
      #pragma unroll 8
      for (int m = 0; m < 32; ++m) {
        float s = sc_[m];
        half2_t v = u2h(vp[(size_t)m*64]);
        a0 += s*(float)v.x; a1 += s*(float)v.y;
      }
      acc5x += a0; acc5y += a1;
    }
  }
  if (t >= 192) {                       // wave-3 ov partials -> LDS
    int j = (t - 128) & 63;
    float2 p; p.x = acc5x; p.y = acc5y;
    *(float2*)(ovh + j*2) = p;
  }
  __syncthreads();

  // ---- P4: normalize; ebar -> eb_l, ov (+vb) -> ov_l ----
  if (t < 128) {
    int ht = t >> 5;
    float inv = 1.0f / (wpart[ht] + wpart[4+ht] + wpart[8+ht] + wpart[12+ht]);
    eb_l[t] = acc4 * inv;
  } else if (t < 192) {
    int j = t - 128, head = j >> 4;
    float inv = 1.0f / (wpart[head] + wpart[4+head] + wpart[8+head] + wpart[12+head]);
    float2 oh = *(const float2*)(ovh + j*2);
    float2 res;
    res.x = (acc5x + oh.x)*inv + ws[OFF_VB + 2*j];
    res.y = (acc5y + oh.y)*inv + ws[OFF_VB + 2*j + 1];
    *(float2*)(ov_l + 2*j) = res;
  }
  __syncthreads();

  // ---- P5: o = ov + vb + WveT@ebar (t<128) ----
  if (t < 128) {
    int hd = t >> 5;
    float acc = ov_l[t];
    const float* wveT = ws + OFF_WVET;
    #pragma unroll 8
    for (int e = 0; e < 32; ++e) acc += wveT[e*128 + t] * eb_l[hd*32 + e];
    o_l[t] = acc;
  }
  __syncthreads();

  // ---- P6: out_w matvec, split-k over 2 halves (all 256 threads) ----
  {
    int d = t & 127, kh = t >> 7;
    const float* owT = ws + OFF_OWT;
    float xa = 0.f;
    #pragma unroll 8
    for (int kk = 0; kk < 64; ++kk) {
      int k = kh*64 + kk;
      xa += owT[k*128 + d] * o_l[k];
    }
    px[kh*128 + d] = xa;
  }
  __syncthreads();

  // ---- P7: residual + LN stats (t<128 holds x in reg) ----
  float x = 0.f;
  if (t < 128) {
    x = px[t] + px[128 + t] + out_b[t] + h_pre;
    float s = x, ss = x*x;
    #pragma unroll
    for (int off = 32; off > 0; off >>= 1) {
      s  += __shfl_down(s,  off);
      ss += __shfl_down(ss, off);
    }
    if ((t & 63) == 0) { stat[t >> 6] = s; stat[2 + (t >> 6)] = ss; }
  }
  __syncthreads();

  // ---- P8: LN + HG -> out ----
  if (t < 128) {
    float mu   = (stat[0] + stat[1]) * (1.0f/128.0f);
    float var  = (stat[2] + stat[3]) * (1.0f/128.0f) - mu*mu;
    float rstd = rsqrtf(var + 1e-5f);
    out[(size_t)bn*128 + t] =
        ln_g[t]*(x - mu)*rstd + ln_b[t] + hg_pre;
  }
}

// ---------------------------------------------------------------------------
extern "C" void kernel_launch(void* const* d_in, const int* in_sizes, int n_in,
                              void* d_out, int out_size, void* d_ws, size_t ws_size,
                              hipStream_t stream) {
  (void)in_sizes; (void)n_in; (void)out_size; (void)ws_size;
  const float* h     = (const float*)d_in[0];
  const float* adj   = (const float*)d_in[1];
  const float* edge  = (const float*)d_in[2];
  const float* srcm  = (const float*)d_in[3];
  const float* gcn_w = (const float*)d_in[4];
  const float* gcn_b = (const float*)d_in[5];
  const float* edge_w= (const float*)d_in[6];
  const float* edge_b= (const float*)d_in[7];
  const float* wq    = (const float*)d_in[8];
  const float* wk    = (const float*)d_in[9];
  const float* wv    = (const float*)d_in[10];
  const float* bq    = (const float*)d_in[11];
  const float* bk    = (const float*)d_in[12];
  const float* bv    = (const float*)d_in[13];
  const float* out_w = (const float*)d_in[14];
  const float* out_b = (const float*)d_in[15];
  const float* ln_g  = (const float*)d_in[16];
  const float* ln_b  = (const float*)d_in[17];

  float* ws  = (float*)d_ws;   // needs >= 3.6 MB
  float* out = (float*)d_out;

  prep_kernel<<<353, 256, 0, stream>>>(wq, wk, wv, out_w, gcn_w, edge_w, edge_b, bk, bv, ws);
  proj_kernel<<<1024, 256, 0, stream>>>(h, adj, bq, gcn_b, ws);
  attn_kernel<<<2048, 256, 0, stream>>>(edge, adj, srcm, h, out_b, ln_g, ln_b, ws, out);
}